// Round 4
// baseline (522.739 us; speedup 1.0000x reference)
//
#include <hip/hip_runtime.h>

// HierarchicalMemory v4: register-cached hot rows + L3-sized residency.
//   M[p,q] = clip(F*Mp[p,q] + (LR*a[p])*b[q], -1, 1) (block-triangular mask);
//   5 attractor iterations, active rows Rt = {400,340,280,200,100}.
// bf16 compression of M failed (R2: absmax 0.39 - the clamped attractor
// amplifies M perturbations ~4000x). So M stays exact fp32:
//   - rows 0..99 (alive all 5 iters = 52% of touches) are computed once in
//     iter 0 and CACHED IN REGISTERS (26 float4/thread, post-clamp fp32).
//   - rows 100..R-1 are re-read from global; with __launch_bounds__(512,2)
//     only 1 block/CU is resident -> live re-read footprint 256*213KB = 54 MB,
//     comfortably inside the 256 MB Infinity Cache.
// Lane l owns column chunks l and 64+l (l<36); h,b in registers; DPP wave64
// reduction (VALU pipe, no LDS); 1-row-ahead prefetch on streamed rows.

#define PDIM 400
#define FORGET 0.9999f
#define LRATE  0.5f
#define DECAY  0.8f
#define SLOPE  0.01f
#define MAXJ 13   // ceil(100/8) cached rows per wave

__device__ __forceinline__ float leaky_clip(float x) {
    x = fminf(fmaxf(x, -1.0f), 1.0f);
    return x > 0.0f ? x : SLOPE * x;
}
__device__ __forceinline__ float clamp1(float x) {
    return fminf(fmaxf(x, -1.0f), 1.0f);
}

// first masked f4-chunk of row p (only used for rows >= 100 here)
__device__ __forceinline__ int c4beg(int p) {
    return (p < 100) ? 0 : (p < 200) ? 25 : (p < 280) ? 50 : (p < 340) ? 70 : 85;
}

// wave64 sum via DPP (verified R1/R2): quad xor1, xor2, half-mirror, mirror,
// row_bcast15, row_bcast31 -> total lands in lane 63; broadcast via readlane.
__device__ __forceinline__ float wave_sum(float x) {
    x += __int_as_float(__builtin_amdgcn_update_dpp(0, __float_as_int(x), 0xB1,  0xf, 0xf, true));
    x += __int_as_float(__builtin_amdgcn_update_dpp(0, __float_as_int(x), 0x4E,  0xf, 0xf, true));
    x += __int_as_float(__builtin_amdgcn_update_dpp(0, __float_as_int(x), 0x141, 0xf, 0xf, true));
    x += __int_as_float(__builtin_amdgcn_update_dpp(0, __float_as_int(x), 0x140, 0xf, 0xf, true));
    x += __int_as_float(__builtin_amdgcn_update_dpp(0, __float_as_int(x), 0x142, 0xf, 0xf, true));
    x += __int_as_float(__builtin_amdgcn_update_dpp(0, __float_as_int(x), 0x143, 0xf, 0xf, true));
    return __int_as_float(__builtin_amdgcn_readlane(__float_as_int(x), 63));
}

__global__ __launch_bounds__(512, 2)
void hier_mem_v4(const float* __restrict__ M_prev,
                 const float* __restrict__ p_inf,
                 const float* __restrict__ p_gen,
                 const float* __restrict__ query,
                 float* __restrict__ out)
{
    __shared__ float s_h[2][PDIM];
    __shared__ float s_la[PDIM];

    const int b   = blockIdx.x;
    const int tid = threadIdx.x;
    const int l   = tid & 63;
    const int wid = tid >> 6;   // 0..7
    const float* __restrict__ Mb = M_prev + (size_t)b * PDIM * PDIM;

    if (tid < PDIM) {
        const float pi = p_inf[b * PDIM + tid];
        const float pg = p_gen[b * PDIM + tid];
        s_la[tid]   = LRATE * (pi - pg);
        s_h[0][tid] = leaky_clip(query[b * PDIM + tid]);
    }

    const float4 z4 = make_float4(0.f, 0.f, 0.f, 0.f);
    const float4* __restrict__ pi4 = (const float4*)(p_inf + (size_t)b * PDIM);
    const float4* __restrict__ pg4 = (const float4*)(p_gen + (size_t)b * PDIM);
    float4 bA, bB = z4;
    {
        const float4 x = pi4[l], y = pg4[l];
        bA = make_float4(x.x + y.x, x.y + y.y, x.z + y.z, x.w + y.w);
        if (l < 36) {
            const float4 u = pi4[64 + l], v = pg4[64 + l];
            bB = make_float4(u.x + v.x, u.y + v.y, u.z + v.z, u.w + v.w);
        }
    }
    __syncthreads();

    // register cache: post-clamp fp32 M for rows wid+8j < 100 (all-iteration rows)
    float4 cacheA[MAXJ];
    float4 cacheB[MAXJ];

    // ------------- iteration 0: stream fp32, fill cache, dot --------------
    {
        const float* __restrict__ hcur = s_h[0];
        float* __restrict__ hnew = s_h[1];
        float4 hA = *(const float4*)(hcur + 4 * l);
        float4 hB = z4;
        if (l < 36) hB = *(const float4*)(hcur + 256 + 4 * l);

        // --- phase A: rows < 100 (c4beg = 0, all lanes active) ---
        float4 pA, pB = z4;
        {
            const float* __restrict__ row = Mb + (size_t)wid * PDIM;
            pA = *(const float4*)(row + 4 * l);
            if (l < 36) pB = *(const float4*)(row + 256 + 4 * l);
        }
        #pragma unroll
        for (int j = 0; j < MAXJ; ++j) {
            const int p = wid + 8 * j;
            if (p < 100) {
                const int pn = p + 8;
                float4 nA = z4, nB = z4;
                if (pn < 100) {
                    const float* __restrict__ rn = Mb + (size_t)pn * PDIM;
                    nA = *(const float4*)(rn + 4 * l);
                    if (l < 36) nB = *(const float4*)(rn + 256 + 4 * l);
                }
                const float la = s_la[p];
                float4 m;
                m.x = clamp1(fmaf(FORGET, pA.x, la * bA.x));
                m.y = clamp1(fmaf(FORGET, pA.y, la * bA.y));
                m.z = clamp1(fmaf(FORGET, pA.z, la * bA.z));
                m.w = clamp1(fmaf(FORGET, pA.w, la * bA.w));
                cacheA[j] = m;
                float acc = fmaf(m.x, hA.x, fmaf(m.y, hA.y, fmaf(m.z, hA.z, m.w * hA.w)));
                float4 mb;
                mb.x = clamp1(fmaf(FORGET, pB.x, la * bB.x));
                mb.y = clamp1(fmaf(FORGET, pB.y, la * bB.y));
                mb.z = clamp1(fmaf(FORGET, pB.z, la * bB.z));
                mb.w = clamp1(fmaf(FORGET, pB.w, la * bB.w));
                cacheB[j] = mb;
                if (l < 36) {
                    acc = fmaf(mb.x, hB.x, fmaf(mb.y, hB.y, fmaf(mb.z, hB.z, fmaf(mb.w, hB.w, acc))));
                }
                const float tot = wave_sum(acc);
                if (l == 0) hnew[p] = leaky_clip(fmaf(DECAY, hcur[p], tot));
                pA = nA; pB = nB;
            }
        }

        // --- phase B: rows 100..399 streaming (masked) ---
        int p = 100 + wid;
        int c4 = c4beg(p);
        float4 cA = z4, cB = z4;
        {
            const float* __restrict__ row = Mb + (size_t)p * PDIM;
            if (l >= c4)                cA = *(const float4*)(row + 4 * l);
            if (l < 36 && 64 + l >= c4) cB = *(const float4*)(row + 256 + 4 * l);
        }
        while (p < PDIM) {
            const int pn = p + 8;
            int c4n = 0;
            float4 nA = z4, nB = z4;
            if (pn < PDIM) {
                c4n = c4beg(pn);
                const float* __restrict__ rn = Mb + (size_t)pn * PDIM;
                if (l >= c4n)                nA = *(const float4*)(rn + 4 * l);
                if (l < 36 && 64 + l >= c4n) nB = *(const float4*)(rn + 256 + 4 * l);
            }
            const float la = s_la[p];
            float acc = 0.f;
            if (l >= c4) {
                float m0 = clamp1(fmaf(FORGET, cA.x, la * bA.x));
                float m1 = clamp1(fmaf(FORGET, cA.y, la * bA.y));
                float m2 = clamp1(fmaf(FORGET, cA.z, la * bA.z));
                float m3 = clamp1(fmaf(FORGET, cA.w, la * bA.w));
                acc = fmaf(m0, hA.x, fmaf(m1, hA.y, fmaf(m2, hA.z, m3 * hA.w)));
            }
            if (l < 36 && 64 + l >= c4) {
                float m0 = clamp1(fmaf(FORGET, cB.x, la * bB.x));
                float m1 = clamp1(fmaf(FORGET, cB.y, la * bB.y));
                float m2 = clamp1(fmaf(FORGET, cB.z, la * bB.z));
                float m3 = clamp1(fmaf(FORGET, cB.w, la * bB.w));
                acc = fmaf(m0, hB.x, fmaf(m1, hB.y, fmaf(m2, hB.z, fmaf(m3, hB.w, acc))));
            }
            const float tot = wave_sum(acc);
            if (l == 0) hnew[p] = leaky_clip(fmaf(DECAY, hcur[p], tot));
            p = pn; c4 = c4n; cA = nA; cB = nB;
        }
        __syncthreads();
    }

    // ------------- iterations 1..4: cached rows + streamed rows -----------
    const int Rt[5] = {400, 340, 280, 200, 100};
    int cur = 1;

    #pragma unroll
    for (int t = 1; t < 5; ++t) {
        const int R = Rt[t];
        const float* __restrict__ hcur = s_h[cur];
        float* __restrict__ hnew = s_h[cur ^ 1];

        float4 hA = *(const float4*)(hcur + 4 * l);
        float4 hB = z4;
        if (l < 36) hB = *(const float4*)(hcur + 256 + 4 * l);

        // cached rows (always < 100 <= R: all active every iteration)
        #pragma unroll
        for (int j = 0; j < MAXJ; ++j) {
            const int p = wid + 8 * j;
            if (p < 100) {
                const float4 m  = cacheA[j];
                float acc = fmaf(m.x, hA.x, fmaf(m.y, hA.y, fmaf(m.z, hA.z, m.w * hA.w)));
                if (l < 36) {
                    const float4 mb = cacheB[j];
                    acc = fmaf(mb.x, hB.x, fmaf(mb.y, hB.y, fmaf(mb.z, hB.z, fmaf(mb.w, hB.w, acc))));
                }
                const float tot = wave_sum(acc);
                if (l == 0) hnew[p] = leaky_clip(fmaf(DECAY, hcur[p], tot));
            }
        }

        // streamed rows 100..R-1 (none in the last iteration)
        int p = 100 + wid;
        if (p < R) {
            int c4 = c4beg(p);
            float4 cA = z4, cB = z4;
            {
                const float* __restrict__ row = Mb + (size_t)p * PDIM;
                if (l >= c4)                cA = *(const float4*)(row + 4 * l);
                if (l < 36 && 64 + l >= c4) cB = *(const float4*)(row + 256 + 4 * l);
            }
            while (p < R) {
                const int pn = p + 8;
                int c4n = 0;
                float4 nA = z4, nB = z4;
                if (pn < R) {
                    c4n = c4beg(pn);
                    const float* __restrict__ rn = Mb + (size_t)pn * PDIM;
                    if (l >= c4n)                nA = *(const float4*)(rn + 4 * l);
                    if (l < 36 && 64 + l >= c4n) nB = *(const float4*)(rn + 256 + 4 * l);
                }
                const float la = s_la[p];
                float acc = 0.f;
                if (l >= c4) {
                    float m0 = clamp1(fmaf(FORGET, cA.x, la * bA.x));
                    float m1 = clamp1(fmaf(FORGET, cA.y, la * bA.y));
                    float m2 = clamp1(fmaf(FORGET, cA.z, la * bA.z));
                    float m3 = clamp1(fmaf(FORGET, cA.w, la * bA.w));
                    acc = fmaf(m0, hA.x, fmaf(m1, hA.y, fmaf(m2, hA.z, m3 * hA.w)));
                }
                if (l < 36 && 64 + l >= c4) {
                    float m0 = clamp1(fmaf(FORGET, cB.x, la * bB.x));
                    float m1 = clamp1(fmaf(FORGET, cB.y, la * bB.y));
                    float m2 = clamp1(fmaf(FORGET, cB.z, la * bB.z));
                    float m3 = clamp1(fmaf(FORGET, cB.w, la * bB.w));
                    acc = fmaf(m0, hB.x, fmaf(m1, hB.y, fmaf(m2, hB.z, fmaf(m3, hB.w, acc))));
                }
                const float tot = wave_sum(acc);
                if (l == 0) hnew[p] = leaky_clip(fmaf(DECAY, hcur[p], tot));
                p = pn; c4 = c4n; cA = nA; cB = nB;
            }
        }

        // frozen rows carry through
        if (tid >= R && tid < PDIM) hnew[tid] = hcur[tid];
        __syncthreads();
        cur ^= 1;
    }

    if (tid < PDIM) out[b * PDIM + tid] = s_h[cur][tid];
}

extern "C" void kernel_launch(void* const* d_in, const int* in_sizes, int n_in,
                              void* d_out, int out_size, void* d_ws, size_t ws_size,
                              hipStream_t stream) {
    const float* M_prev = (const float*)d_in[0];
    const float* p_inf  = (const float*)d_in[1];
    const float* p_gen  = (const float*)d_in[2];
    const float* query  = (const float*)d_in[3];
    float* out = (float*)d_out;

    const int B = in_sizes[1] / PDIM;   // 512
    hipLaunchKernelGGL(hier_mem_v4, dim3(B), dim3(512), 0, stream,
                       M_prev, p_inf, p_gen, query, out);
}